// Round 5
// baseline (131.373 us; speedup 1.0000x reference)
//
#include <hip/hip_runtime.h>
#include <hip/hip_bf16.h>

typedef float f32x4  __attribute__((ext_vector_type(4)));
typedef short bf16x8 __attribute__((ext_vector_type(8)));

__device__ __forceinline__ short bf16r(float x) {
    unsigned u = __builtin_bit_cast(unsigned, x);
    u += 0x7fffu + ((u >> 16) & 1u);
    return (short)(u >> 16);
}

// prepass: head (2M) + dep (2M) f32 -> bf16 into ws
__global__ void cvt_kernel(const float* __restrict__ head, const float* __restrict__ dep,
                           short* __restrict__ hb, short* __restrict__ db) {
    const int n8 = 8 * 512 * 512 / 8;
    int i = blockIdx.x * blockDim.x + threadIdx.x;
    const float* src = (i < n8) ? head : dep;
    short* dst = (i < n8) ? hb : db;
    int j = (i < n8) ? i : i - n8;
    f32x4 a = *(const f32x4*)(src + (size_t)j * 8);
    f32x4 c = *(const f32x4*)(src + (size_t)j * 8 + 4);
    bf16x8 v;
#pragma unroll
    for (int e = 0; e < 4; ++e) { v[e] = bf16r(a[e]); v[4 + e] = bf16r(c[e]); }
    *(bf16x8*)(dst + (size_t)j * 8) = v;
}

// ---- main: 128x128 tile, 4 waves (2Mx2N, wave 64x64), BK=64, dbuf LDS 64KB
// ---- -> 2 blocks/CU so epilogue HBM drain overlaps the other block's K-loop.
__global__ __launch_bounds__(256, 2)
void bla_gemm5(const short* __restrict__ headb,
               const short* __restrict__ depb,
               const float* __restrict__ U,
               float* __restrict__ out)
{
    constexpr int S = 512, D = 512, L = 32, BM = 128, BN = 128, BK = 64, NT = 8;

    __shared__ __align__(16) short Al[2][BM * BK];   // 16KB each
    __shared__ __align__(16) short Bl[2][BN * BK];   // total 64KB

    const int tid = threadIdx.x, lane = tid & 63, wid = tid >> 6;
    const int wm = wid >> 1, wn = wid & 1;           // wave tile 64x64

    // XCD swizzle: 4096 blocks, 512/XCD = one b per XCD.
    // Within XCD: (it,ot) outer, l inner -> same head/dep 128-row panels stay
    // L2-hot across 32 consecutive l blocks.
    const int swz = (blockIdx.x & 7) * ((int)gridDim.x >> 3) + (blockIdx.x >> 3);
    const int b = swz >> 9, rem = swz & 511;
    const int it = rem >> 7, ot = (rem >> 5) & 3, l = rem & 31;
    const int i0 = it * BM, o0 = ot * BN;

    // A staging: 256 thr; row = tid>>2 (0..63, 2 passes of 64), col = (tid&3)*16
    const int arow = tid >> 2, acol = (tid & 3) * 16;
    const short* hbase = headb + (size_t)(b * S + i0 + arow) * D + acol;
    const float* ubase = U + (size_t)l * D + acol;
    const int asw0 = (((acol * 2) ^ ((arow & 7) << 4)) >> 1);        // chunk q=0
    const int asw1 = (((acol * 2 + 16) ^ ((arow & 7) << 4)) >> 1);   // chunk q=1

    // B gload: linear LDS dest, inverse-swizzled global source (rule #21)
    const int bso = ((lane & 7) * 16) ^ ((lane >> 3) << 4);
    const short* dbase = depb + (size_t)(b * S + o0) * D;

    bf16x8 rA[2][4];    // [tile parity][pass*2+chunk]
    f32x4  ru[2][4];    // [tile parity][j] covering cols acol + j*4

#define SBAR() __builtin_amdgcn_sched_barrier(0)
#define BAR()  __builtin_amdgcn_s_barrier()

    // 8 loads per issue: 4 x bf16x8 (A) + 4 x f32x4 (U)
#define A_ISSUE(tt) do {                                                        \
        const int s_ = (tt) & 1;                                                \
        _Pragma("unroll")                                                       \
        for (int p = 0; p < 2; ++p)                                             \
            _Pragma("unroll")                                                   \
            for (int q = 0; q < 2; ++q)                                         \
                rA[s_][p * 2 + q] = *(const bf16x8*)(hbase +                    \
                    (size_t)(p * 64) * D + (tt) * BK + q * 8);                  \
        _Pragma("unroll")                                                       \
        for (int j = 0; j < 4; ++j)                                             \
            ru[s_][j] = *(const f32x4*)(ubase + (tt) * BK + j * 4);             \
    } while (0)

    // write pass p (64 rows) of tile tt into Al[(tt)&1]; scale by U, cvt bf16
#define A_WRITE_P(tt, p) do {                                                   \
        const int s_ = (tt) & 1;                                                \
        _Pragma("unroll")                                                       \
        for (int q = 0; q < 2; ++q) {                                           \
            bf16x8 av;                                                          \
            _Pragma("unroll")                                                   \
            for (int e = 0; e < 8; ++e) {                                       \
                float f = __builtin_bit_cast(float,                             \
                    (unsigned)((unsigned short)rA[s_][(p) * 2 + q][e]) << 16)   \
                    * ru[s_][q * 2 + (e >> 2)][e & 3];                          \
                av[e] = __builtin_bit_cast(short, __float2bfloat16(f));         \
            }                                                                   \
            *(bf16x8*)&Al[s_][(arow + (p) * 64) * BK + (q ? asw1 : asw0)] = av; \
        }                                                                       \
    } while (0)

    // 4 gload_lds per wave: 16KB B tile for tile tt into Bl[(tt)&1]
#define B_ISSUE(tt) do {                                                        \
        _Pragma("unroll")                                                       \
        for (int q = 0; q < 4; ++q) {                                           \
            const int rg = wid * 32 + q * 8 + (lane >> 3);                      \
            const char* s_ = (const char*)dbase +                               \
                ((size_t)rg * D + (size_t)(tt) * BK) * 2 + bso;                 \
            __builtin_amdgcn_global_load_lds(                                   \
                (const __attribute__((address_space(1))) void*)s_,              \
                (__attribute__((address_space(3))) void*)&Bl[(tt) & 1][(wid * 32 + q * 8) * BK], \
                16, 0, 0);                                                      \
        }                                                                       \
    } while (0)

    f32x4 acc[4][4] = {};
    bf16x8 bfr[4];

#define DSREAD_A(buf_, ks_, af_) do {                                           \
        const int cb = (ks_) * 64 + ((lane >> 4) << 4);                         \
        _Pragma("unroll")                                                       \
        for (int f = 0; f < 4; ++f) {                                           \
            const int row = wm * 64 + f * 16 + (lane & 15);                     \
            af_[f] = *(const bf16x8*)&Al[buf_][row * BK + ((cb ^ ((row & 7) << 4)) >> 1)]; \
        }                                                                       \
    } while (0)

#define DSREAD_B(buf_, ks_) do {                                                \
        const int cb = (ks_) * 64 + ((lane >> 4) << 4);                         \
        _Pragma("unroll")                                                       \
        for (int f = 0; f < 4; ++f) {                                           \
            const int row = wn * 64 + f * 16 + (lane & 15);                     \
            bfr[f] = *(const bf16x8*)&Bl[buf_][row * BK + ((cb ^ ((row & 7) << 4)) >> 1)]; \
        }                                                                       \
    } while (0)

#define MFMA16(af_) do {                                                        \
        __builtin_amdgcn_s_setprio(1);                                          \
        _Pragma("unroll")                                                       \
        for (int m = 0; m < 4; ++m)                                             \
            _Pragma("unroll")                                                   \
            for (int n = 0; n < 4; ++n)                                         \
                acc[m][n] = __builtin_amdgcn_mfma_f32_16x16x32_bf16(            \
                    af_[m], bfr[n], acc[m][n], 0, 0, 0);                        \
        __builtin_amdgcn_s_setprio(0);                                          \
    } while (0)

    // ---- prologue: stage tile0; prefetch A(1); counted drain of B(0) only
    A_ISSUE(0);
    B_ISSUE(0);
    SBAR();
    A_WRITE_P(0, 0); A_WRITE_P(0, 1);   // auto vmcnt(4): waits A(0)+U(0), B in flight
    A_ISSUE(1);
    SBAR();
    asm volatile("s_waitcnt vmcnt(8) lgkmcnt(0)" ::: "memory");  // B(0) done; A(1)x8 in flight
    SBAR();
    BAR();
    SBAR();

#pragma unroll
    for (int t = 0; t < NT; ++t) {
        const int c = t & 1;
        bf16x8 af[4];

        // ---------- ph0: ks0; issue B(t+1); write A(t+1) pass 0
        DSREAD_A(c, 0, af); DSREAD_B(c, 0);
        if (t + 1 < NT) { B_ISSUE(t + 1); A_WRITE_P(t + 1, 0); }
        SBAR(); BAR(); SBAR();
        MFMA16(af);
        SBAR(); BAR(); SBAR();

        // ---------- ph1: ks1; write A(t+1) pass 1; prefetch A(t+2); counted tile-end wait
        DSREAD_A(c, 1, af); DSREAD_B(c, 1);
        if (t + 1 < NT) A_WRITE_P(t + 1, 1);
        if (t + 2 < NT) A_ISSUE(t + 2);
        SBAR(); BAR(); SBAR();
        MFMA16(af);
        SBAR();
        if (t + 2 < NT) {
            // outstanding: B(t+1)=4 oldest, A(t+2)+U(t+2)=8 newer -> wait B only
            asm volatile("s_waitcnt vmcnt(8) lgkmcnt(0)" ::: "memory");
        } else if (t + 1 < NT) {
            asm volatile("s_waitcnt vmcnt(0) lgkmcnt(0)" ::: "memory");
        }
        SBAR(); BAR(); SBAR();
    }

    // ---- epilogue: C/D layout col=lane&15, row=(lane>>4)*4+r
    float* op = out + (size_t)(b * L + l) * S * S;
#pragma unroll
    for (int m = 0; m < 4; ++m) {
        const int row0 = i0 + wm * 64 + m * 16 + ((lane >> 4) << 2);
#pragma unroll
        for (int n = 0; n < 4; ++n) {
            const int col = o0 + wn * 64 + n * 16 + (lane & 15);
#pragma unroll
            for (int r = 0; r < 4; ++r)
                op[(size_t)(row0 + r) * S + col] = acc[m][n][r];
        }
    }

#undef SBAR
#undef BAR
#undef A_ISSUE
#undef A_WRITE_P
#undef B_ISSUE
#undef DSREAD_A
#undef DSREAD_B
#undef MFMA16
}

// ---------------- fallback (proven R1 kernel): used only if ws < 8MB ----------
__global__ __launch_bounds__(256, 2)
void bla_fb(const float* __restrict__ head, const float* __restrict__ dep,
            const float* __restrict__ U, float* __restrict__ out)
{
    constexpr int S = 512, D = 512, L = 32, BM = 128, BN = 128, BK = 64, NT = 8;
    __shared__ short Al[2][BM * BK];
    __shared__ short Bl[2][BN * BK];
    const int tid = threadIdx.x, lane = tid & 63, wid = tid >> 6;
    const int wm = wid >> 1, wn = wid & 1;
    const int swz = (blockIdx.x & 7) * ((int)gridDim.x >> 3) + (blockIdx.x >> 3);
    const int b = swz >> 9, rem = swz & 511;
    const int l = rem >> 4, it = (rem >> 2) & 3, ot = rem & 3;
    const int i0 = it * BM, o0 = ot * BN;
    const int srow = tid >> 3, scol = (tid & 7) * 8, swb = scol * 2;
    const float* hb = head + (size_t)(b * S + i0 + srow) * D + scol;
    const float* db = dep + (size_t)(b * S + o0 + srow) * D + scol;
    const float* ub = U + l * D + scol;
    f32x4 ra[4][2], rb[4][2], ru[2];
#define FSTAGE_LOAD(t) do { const int k0_ = (t) * BK;                              \
        ru[0] = *(const f32x4*)(ub + k0_); ru[1] = *(const f32x4*)(ub + k0_ + 4);  \
        _Pragma("unroll") for (int p_ = 0; p_ < 4; ++p_) {                         \
            ra[p_][0] = *(const f32x4*)(hb + k0_ + p_ * 32 * D);                   \
            ra[p_][1] = *(const f32x4*)(hb + k0_ + p_ * 32 * D + 4);               \
            rb[p_][0] = *(const f32x4*)(db + k0_ + p_ * 32 * D);                   \
            rb[p_][1] = *(const f32x4*)(db + k0_ + p_ * 32 * D + 4); } } while (0)
#define FSTAGE_WRITE(buf) do { _Pragma("unroll") for (int p_ = 0; p_ < 4; ++p_) {  \
            const int row_ = srow + p_ * 32; const int sb_ = swb ^ ((row_ & 7) << 4); \
            bf16x8 av_, bv_;                                                       \
            _Pragma("unroll") for (int q_ = 0; q_ < 2; ++q_)                       \
                _Pragma("unroll") for (int j_ = 0; j_ < 4; ++j_) {                 \
                    av_[q_ * 4 + j_] = bf16r(ra[p_][q_][j_] * ru[q_][j_]);         \
                    bv_[q_ * 4 + j_] = bf16r(rb[p_][q_][j_]); }                    \
            *(bf16x8*)&Al[buf][row_ * BK + (sb_ >> 1)] = av_;                      \
            *(bf16x8*)&Bl[buf][row_ * BK + (sb_ >> 1)] = bv_; } } while (0)
    f32x4 acc[4][4] = {};
    const int cbase = (lane >> 4) << 4, rsw = (lane & 7) << 4;
#define FCOMPUTE(buf) do { _Pragma("unroll") for (int ks_ = 0; ks_ < 2; ++ks_) {   \
            const int sb2_ = (ks_ * 64 + cbase) ^ rsw; bf16x8 af_[4], bfr_[4];     \
            _Pragma("unroll") for (int f_ = 0; f_ < 4; ++f_) {                     \
                af_[f_] = *(const bf16x8*)&Al[buf][(wm * 64 + f_ * 16 + (lane & 15)) * BK + (sb2_ >> 1)]; \
                bfr_[f_] = *(const bf16x8*)&Bl[buf][(wn * 64 + f_ * 16 + (lane & 15)) * BK + (sb2_ >> 1)]; } \
            _Pragma("unroll") for (int fm_ = 0; fm_ < 4; ++fm_)                    \
                _Pragma("unroll") for (int fn_ = 0; fn_ < 4; ++fn_)                \
                    acc[fm_][fn_] = __builtin_amdgcn_mfma_f32_16x16x32_bf16(       \
                        af_[fm_], bfr_[fn_], acc[fm_][fn_], 0, 0, 0); } } while (0)
    FSTAGE_LOAD(0); FSTAGE_WRITE(0); __syncthreads();
    int cur = 0;
#pragma unroll
    for (int t = 0; t < NT; ++t) {
        if (t + 1 < NT) FSTAGE_LOAD(t + 1);
        FCOMPUTE(cur);
        if (t + 1 < NT) FSTAGE_WRITE(cur ^ 1);
        __syncthreads();
        cur ^= 1;
    }
    float* op = out + (size_t)(b * L + l) * S * S;
#pragma unroll
    for (int fm = 0; fm < 4; ++fm) {
        const int row0 = i0 + wm * 64 + fm * 16 + ((lane >> 4) << 2);
#pragma unroll
        for (int fn = 0; fn < 4; ++fn) {
            const int col = o0 + wn * 64 + fn * 16 + (lane & 15);
#pragma unroll
            for (int r = 0; r < 4; ++r)
                op[(size_t)(row0 + r) * S + col] = acc[fm][fn][r];
        }
    }
#undef FSTAGE_LOAD
#undef FSTAGE_WRITE
#undef FCOMPUTE
}

extern "C" void kernel_launch(void* const* d_in, const int* in_sizes, int n_in,
                              void* d_out, int out_size, void* d_ws, size_t ws_size,
                              hipStream_t stream)
{
    const float* head = (const float*)d_in[0];
    const float* dep  = (const float*)d_in[1];
    const float* U    = (const float*)d_in[2];
    float* out        = (float*)d_out;

    const size_t nelem = (size_t)8 * 512 * 512;
    const size_t need  = nelem * 2 * 2;   // 8MB
    if (ws_size >= need) {
        short* headb = (short*)d_ws;
        short* depb  = headb + nelem;
        cvt_kernel<<<dim3(2048), dim3(256), 0, stream>>>(head, dep, headb, depb);
        bla_gemm5<<<dim3(4096), dim3(256), 0, stream>>>(headb, depb, U, out);
    } else {
        bla_fb<<<dim3(4096), dim3(256), 0, stream>>>(head, dep, U, out);
    }
}